// Round 1
// baseline (881.902 us; speedup 1.0000x reference)
//
#include <hip/hip_runtime.h>

// Problem: B=64, C=256, H=W=32 -> N=1024 positions, 32 groups.
// Pipeline: GN -> qkv proj -> attention (d=256, seq=1024, per batch) -> out proj -> residual.
// All matmuls in bf16 MFMA (16x16x32). q scaled by C^-0.5=1/16 folded into wq/bq.

#define BB 64
#define CC 256
#define NN 1024

typedef float  floatx4  __attribute__((ext_vector_type(4)));
typedef short  shortx8  __attribute__((ext_vector_type(8)));
typedef unsigned short ushortx4 __attribute__((ext_vector_type(4)));
typedef unsigned short ushortx8 __attribute__((ext_vector_type(8)));

__device__ __forceinline__ unsigned short f2bf(float f) {
  union { float f; unsigned int u; } cv; cv.f = f;
  unsigned int u = cv.u;
  u += 0x7fffu + ((u >> 16) & 1u);
  return (unsigned short)(u >> 16);
}

__device__ __forceinline__ floatx4 mfma16(shortx8 a, shortx8 b, floatx4 c) {
  return __builtin_amdgcn_mfma_f32_16x16x32_bf16(a, b, c, 0, 0, 0);
}

// ---------------- weight conversion ----------------
// Wqkv (768x256) bf16: rows 0..255 = wq/16, 256..511 = wk, 512..767 = wv
// wo_bf (256x256) bf16; bqkv (768) f32 with bq/16.
__global__ void convert_w(const float* __restrict__ wq, const float* __restrict__ bq,
                          const float* __restrict__ wk, const float* __restrict__ bk,
                          const float* __restrict__ wv, const float* __restrict__ bv,
                          const float* __restrict__ wo,
                          unsigned short* __restrict__ wqkv,
                          unsigned short* __restrict__ wo_bf,
                          float* __restrict__ bqkv) {
  int i = blockIdx.x * 256 + threadIdx.x;
  if (i < 196608) {
    int o = i >> 8, c = i & 255;
    float val;
    if (o < 256)      val = wq[o * 256 + c] * 0.0625f;
    else if (o < 512) val = wk[(o - 256) * 256 + c];
    else              val = wv[(o - 512) * 256 + c];
    wqkv[i] = f2bf(val);
  } else if (i < 262144) {
    int j = i - 196608;
    wo_bf[j] = f2bf(wo[j]);
  } else if (i < 262912) {
    int o = i - 262144;
    float val;
    if (o < 256)      val = bq[o] * 0.0625f;
    else if (o < 512) val = bk[o - 256];
    else              val = bv[o - 512];
    bqkv[o] = val;
  }
}

// ---------------- GroupNorm -> h_t (B, N, C) bf16 ----------------
// block = (group g, batch b); 256 threads; 8 channels x 1024 positions per group.
__global__ __launch_bounds__(256) void gn_kernel(const float* __restrict__ x,
                                                 const float* __restrict__ gw,
                                                 const float* __restrict__ gb,
                                                 unsigned short* __restrict__ h_t) {
  int g = blockIdx.x, b = blockIdx.y;
  int t = threadIdx.x;
  const float* xb = x + ((size_t)b * CC + g * 8) * NN;

  float vals[8][4];
  float s = 0.f, sq = 0.f;
#pragma unroll
  for (int cc = 0; cc < 8; cc++) {
    floatx4 v4 = *(const floatx4*)(xb + cc * NN + t * 4);
#pragma unroll
    for (int j = 0; j < 4; j++) {
      vals[cc][j] = v4[j];
      s += v4[j];
      sq += v4[j] * v4[j];
    }
  }
#pragma unroll
  for (int d = 1; d < 64; d <<= 1) {
    s  += __shfl_xor(s, d);
    sq += __shfl_xor(sq, d);
  }
  __shared__ float ssum[4], ssq[4];
  int w = t >> 6;
  if ((t & 63) == 0) { ssum[w] = s; ssq[w] = sq; }
  __syncthreads();
  s  = ssum[0] + ssum[1] + ssum[2] + ssum[3];
  sq = ssq[0] + ssq[1] + ssq[2] + ssq[3];
  float mean = s * (1.f / 8192.f);
  float var  = sq * (1.f / 8192.f) - mean * mean;
  float rstd = rsqrtf(var + 1e-5f);

  float gam[8], bet[8];
#pragma unroll
  for (int cc = 0; cc < 8; cc++) {
    float gm = gw[g * 8 + cc] * rstd;
    gam[cc] = gm;
    bet[cc] = gb[g * 8 + cc] - mean * gm;
  }
  unsigned short* hb = h_t + (size_t)b * NN * CC + g * 8;
#pragma unroll
  for (int j = 0; j < 4; j++) {
    ushortx8 pk;
#pragma unroll
    for (int cc = 0; cc < 8; cc++) pk[cc] = f2bf(vals[cc][j] * gam[cc] + bet[cc]);
    *(ushortx8*)(hb + (size_t)(t * 4 + j) * CC) = pk;
  }
}

// ---------------- QKV GEMM ----------------
// Per batch: D[n][o'] = sum_c h_t[n][c] * Wqkv[o'][c]   (M=1024, N'=768, K=256)
// q_t,k_t stored (N,C); v stored (C,N).
__global__ __launch_bounds__(256) void qkv_gemm(const unsigned short* __restrict__ h_t,
                                                const unsigned short* __restrict__ wqkv,
                                                const float* __restrict__ bqkv,
                                                unsigned short* __restrict__ q_t,
                                                unsigned short* __restrict__ k_t,
                                                unsigned short* __restrict__ v) {
  int b = blockIdx.z;
  int n0 = blockIdx.y * 64, o0 = blockIdx.x * 64;
  int t = threadIdx.x, w = t >> 6, l = t & 63, lo = l & 15, h = l >> 4;
  int wr = w >> 1, wc = w & 1;
  const unsigned short* A = h_t + (size_t)b * NN * CC;
  int arow0 = n0 + wr * 32, bcol0 = o0 + wc * 32;

  floatx4 zero4 = {0.f, 0.f, 0.f, 0.f};
  floatx4 acc[2][2];
  acc[0][0] = zero4; acc[0][1] = zero4; acc[1][0] = zero4; acc[1][1] = zero4;

#pragma unroll
  for (int kc = 0; kc < 8; kc++) {
    int c0 = kc * 32 + h * 8;
    shortx8 a0 = *(const shortx8*)(A + (size_t)(arow0 + lo) * CC + c0);
    shortx8 a1 = *(const shortx8*)(A + (size_t)(arow0 + 16 + lo) * CC + c0);
    shortx8 b0 = *(const shortx8*)(wqkv + (size_t)(bcol0 + lo) * CC + c0);
    shortx8 b1 = *(const shortx8*)(wqkv + (size_t)(bcol0 + 16 + lo) * CC + c0);
    acc[0][0] = mfma16(a0, b0, acc[0][0]);
    acc[0][1] = mfma16(a0, b1, acc[0][1]);
    acc[1][0] = mfma16(a1, b0, acc[1][0]);
    acc[1][1] = mfma16(a1, b1, acc[1][1]);
  }
#pragma unroll
  for (int i = 0; i < 2; i++) {
#pragma unroll
    for (int j = 0; j < 2; j++) {
      int o = bcol0 + j * 16 + lo;
      float bias = bqkv[o];
      if (o < 512) {
#pragma unroll
        for (int r = 0; r < 4; r++) {
          int n = arow0 + i * 16 + h * 4 + r;
          float val = acc[i][j][r] + bias;
          if (o < 256)
            q_t[((size_t)b * NN + n) * CC + o] = f2bf(val);
          else
            k_t[((size_t)b * NN + n) * CC + (o - 256)] = f2bf(val);
        }
      } else {
        int n0r = arow0 + i * 16 + h * 4;
        ushortx4 pk;
#pragma unroll
        for (int r = 0; r < 4; r++) pk[r] = f2bf(acc[i][j][r] + bias);
        *(ushortx4*)(v + ((size_t)b * CC + (o - 512)) * NN + n0r) = pk;
      }
    }
  }
}

// ---------------- Flash attention ----------------
// block = (16-query-tile x 4 waves = 64 queries, batch). d=256, seq=1024.
__global__ __launch_bounds__(256) void flash_kernel(const unsigned short* __restrict__ q_t,
                                                    const unsigned short* __restrict__ k_t,
                                                    const unsigned short* __restrict__ v,
                                                    unsigned short* __restrict__ attn_t) {
  int qblk = blockIdx.x, b = blockIdx.y;
  int t = threadIdx.x, w = t >> 6, l = t & 63, lo = l & 15, h = l >> 4;
  const unsigned short* qtb = q_t + (size_t)b * NN * CC;
  const unsigned short* ktb = k_t + (size_t)b * NN * CC;
  const unsigned short* vb  = v   + (size_t)b * CC * NN;
  int qbase = qblk * 64 + w * 16;

  shortx8 qf[8];
#pragma unroll
  for (int ch = 0; ch < 8; ch++)
    qf[ch] = *(const shortx8*)(qtb + (size_t)(qbase + lo) * CC + ch * 32 + h * 8);

  floatx4 zero4 = {0.f, 0.f, 0.f, 0.f};
  floatx4 o[16];
#pragma unroll
  for (int i = 0; i < 16; i++) o[i] = zero4;
  float m[4], lsum[4];
#pragma unroll
  for (int r = 0; r < 4; r++) { m[r] = -1e30f; lsum[r] = 0.f; }

  __shared__ unsigned short Pl[4][16][72];  // per-wave P tile, padded rows (144B)

  for (int kb = 0; kb < 16; kb++) {
    int k0 = kb * 64;
    floatx4 s[4];
#pragma unroll
    for (int i = 0; i < 4; i++) s[i] = zero4;
#pragma unroll
    for (int kt = 0; kt < 4; kt++) {
      const unsigned short* kp = ktb + (size_t)(k0 + kt * 16 + lo) * CC + h * 8;
#pragma unroll
      for (int ch = 0; ch < 8; ch++) {
        shortx8 kf = *(const shortx8*)(kp + ch * 32);
        s[kt] = mfma16(qf[ch], kf, s[kt]);
      }
    }
    // online softmax (rows q = h*4+r, cols spread over 16 lanes of the h-group)
#pragma unroll
    for (int r = 0; r < 4; r++) {
      float mx = fmaxf(fmaxf(s[0][r], s[1][r]), fmaxf(s[2][r], s[3][r]));
#pragma unroll
      for (int d = 1; d < 16; d <<= 1) mx = fmaxf(mx, __shfl_xor(mx, d));
      float mn = fmaxf(m[r], mx);
      float alpha = __expf(m[r] - mn);
      float rs = 0.f;
#pragma unroll
      for (int kt = 0; kt < 4; kt++) {
        float p = __expf(s[kt][r] - mn);
        rs += p;
        Pl[w][h * 4 + r][kt * 16 + lo] = f2bf(p);
      }
#pragma unroll
      for (int d = 1; d < 16; d <<= 1) rs += __shfl_xor(rs, d);
      lsum[r] = lsum[r] * alpha + rs;
      m[r] = mn;
#pragma unroll
      for (int cb = 0; cb < 16; cb++) o[cb][r] *= alpha;
    }
    // PV: O[q][c] += P[q][m] * v[c][m]
#pragma unroll
    for (int kk = 0; kk < 2; kk++) {
      shortx8 pa = *(const shortx8*)(&Pl[w][lo][kk * 32 + h * 8]);
#pragma unroll
      for (int cb = 0; cb < 16; cb++) {
        shortx8 vf = *(const shortx8*)(vb + (size_t)(cb * 16 + lo) * NN + k0 + kk * 32 + h * 8);
        o[cb] = mfma16(pa, vf, o[cb]);
      }
    }
  }

  unsigned short* ab = attn_t + (size_t)b * NN * CC;
#pragma unroll
  for (int cb = 0; cb < 16; cb++) {
#pragma unroll
    for (int r = 0; r < 4; r++) {
      float val = o[cb][r] / lsum[r];
      ab[(size_t)(qbase + h * 4 + r) * CC + cb * 16 + lo] = f2bf(val);
    }
  }
}

// ---------------- Out projection + bias + residual ----------------
// D[n][o] = sum_c attn_t[n][c] * wo[o][c];  out[b][o][n] = x + D + bo
__global__ __launch_bounds__(256) void outproj_gemm(const unsigned short* __restrict__ attn_t,
                                                    const unsigned short* __restrict__ wo_bf,
                                                    const float* __restrict__ bo,
                                                    const float* __restrict__ x,
                                                    float* __restrict__ out) {
  int b = blockIdx.z;
  int n0 = blockIdx.y * 64, o0 = blockIdx.x * 64;
  int t = threadIdx.x, w = t >> 6, l = t & 63, lo = l & 15, h = l >> 4;
  int wr = w >> 1, wc = w & 1;
  const unsigned short* A = attn_t + (size_t)b * NN * CC;
  int arow0 = n0 + wr * 32, bcol0 = o0 + wc * 32;

  floatx4 zero4 = {0.f, 0.f, 0.f, 0.f};
  floatx4 acc[2][2];
  acc[0][0] = zero4; acc[0][1] = zero4; acc[1][0] = zero4; acc[1][1] = zero4;

#pragma unroll
  for (int kc = 0; kc < 8; kc++) {
    int c0 = kc * 32 + h * 8;
    shortx8 a0 = *(const shortx8*)(A + (size_t)(arow0 + lo) * CC + c0);
    shortx8 a1 = *(const shortx8*)(A + (size_t)(arow0 + 16 + lo) * CC + c0);
    shortx8 b0 = *(const shortx8*)(wo_bf + (size_t)(bcol0 + lo) * CC + c0);
    shortx8 b1 = *(const shortx8*)(wo_bf + (size_t)(bcol0 + 16 + lo) * CC + c0);
    acc[0][0] = mfma16(a0, b0, acc[0][0]);
    acc[0][1] = mfma16(a0, b1, acc[0][1]);
    acc[1][0] = mfma16(a1, b0, acc[1][0]);
    acc[1][1] = mfma16(a1, b1, acc[1][1]);
  }
#pragma unroll
  for (int i = 0; i < 2; i++) {
#pragma unroll
    for (int j = 0; j < 2; j++) {
      int o = bcol0 + j * 16 + lo;
      int n = arow0 + i * 16 + h * 4;
      float bias = bo[o];
      size_t idx = ((size_t)b * CC + o) * NN + n;
      floatx4 xr = *(const floatx4*)(x + idx);
      floatx4 res;
#pragma unroll
      for (int r = 0; r < 4; r++) res[r] = acc[i][j][r] + bias + xr[r];
      *(floatx4*)(out + idx) = res;
    }
  }
}

extern "C" void kernel_launch(void* const* d_in, const int* in_sizes, int n_in,
                              void* d_out, int out_size, void* d_ws, size_t ws_size,
                              hipStream_t stream) {
  const float* x  = (const float*)d_in[0];
  const float* gw = (const float*)d_in[1];
  const float* gb = (const float*)d_in[2];
  const float* wq = (const float*)d_in[3];
  const float* bq = (const float*)d_in[4];
  const float* wk = (const float*)d_in[5];
  const float* bk = (const float*)d_in[6];
  const float* wv = (const float*)d_in[7];
  const float* bv = (const float*)d_in[8];
  const float* wo = (const float*)d_in[9];
  const float* bo = (const float*)d_in[10];
  float* out = (float*)d_out;

  char* ws = (char*)d_ws;
  // ws layout (bytes): total ~128.5 MB
  unsigned short* q_t   = (unsigned short*)(ws);                 // 33554432 B
  unsigned short* k_t   = (unsigned short*)(ws + 33554432);      // 33554432 B
  unsigned short* v     = (unsigned short*)(ws + 67108864);      // 33554432 B
  unsigned short* h_t   = (unsigned short*)(ws + 100663296);     // 33554432 B (reused as attn_t)
  unsigned short* wqkv  = (unsigned short*)(ws + 134217728);     // 393216 B
  unsigned short* wo_bf = (unsigned short*)(ws + 134610944);     // 131072 B
  float*          bqkv  = (float*)(ws + 134742016);              // 3072 B
  unsigned short* attn_t = h_t;

  convert_w<<<dim3(1027), dim3(256), 0, stream>>>(wq, bq, wk, bk, wv, bv, wo, wqkv, wo_bf, bqkv);
  gn_kernel<<<dim3(32, 64), dim3(256), 0, stream>>>(x, gw, gb, h_t);
  qkv_gemm<<<dim3(12, 16, 64), dim3(256), 0, stream>>>(h_t, wqkv, bqkv, q_t, k_t, v);
  flash_kernel<<<dim3(16, 64), dim3(256), 0, stream>>>(q_t, k_t, v, attn_t);
  outproj_gemm<<<dim3(4, 16, 64), dim3(256), 0, stream>>>(attn_t, wo_bf, bo, x, out);
}

// Round 2
// 767.280 us; speedup vs baseline: 1.1494x; 1.1494x over previous
//
#include <hip/hip_runtime.h>

// Problem: B=64, C=256, H=W=32 -> N=1024 positions, 32 groups.
// Pipeline: GN -> qkv proj -> attention (d=256, seq=1024, per batch) -> out proj -> residual.
// All matmuls in bf16 MFMA (16x16x32). q scaled by C^-0.5=1/16 folded into wq/bq.

#define BB 64
#define CC 256
#define NN 1024

typedef float  floatx4  __attribute__((ext_vector_type(4)));
typedef short  shortx8  __attribute__((ext_vector_type(8)));
typedef unsigned short ushortx4 __attribute__((ext_vector_type(4)));
typedef unsigned short ushortx8 __attribute__((ext_vector_type(8)));

__device__ __forceinline__ unsigned short f2bf(float f) {
  union { float f; unsigned int u; } cv; cv.f = f;
  unsigned int u = cv.u;
  u += 0x7fffu + ((u >> 16) & 1u);
  return (unsigned short)(u >> 16);
}

__device__ __forceinline__ floatx4 mfma16(shortx8 a, shortx8 b, floatx4 c) {
  return __builtin_amdgcn_mfma_f32_16x16x32_bf16(a, b, c, 0, 0, 0);
}

// ---------------- weight conversion ----------------
__global__ void convert_w(const float* __restrict__ wq, const float* __restrict__ bq,
                          const float* __restrict__ wk, const float* __restrict__ bk,
                          const float* __restrict__ wv, const float* __restrict__ bv,
                          const float* __restrict__ wo,
                          unsigned short* __restrict__ wqkv,
                          unsigned short* __restrict__ wo_bf,
                          float* __restrict__ bqkv) {
  int i = blockIdx.x * 256 + threadIdx.x;
  if (i < 196608) {
    int o = i >> 8, c = i & 255;
    float val;
    if (o < 256)      val = wq[o * 256 + c] * 0.0625f;
    else if (o < 512) val = wk[(o - 256) * 256 + c];
    else              val = wv[(o - 512) * 256 + c];
    wqkv[i] = f2bf(val);
  } else if (i < 262144) {
    int j = i - 196608;
    wo_bf[j] = f2bf(wo[j]);
  } else if (i < 262912) {
    int o = i - 262144;
    float val;
    if (o < 256)      val = bq[o] * 0.0625f;
    else if (o < 512) val = bk[o - 256];
    else              val = bv[o - 512];
    bqkv[o] = val;
  }
}

// ---------------- GroupNorm -> h_t (B, N, C) bf16 ----------------
__global__ __launch_bounds__(256) void gn_kernel(const float* __restrict__ x,
                                                 const float* __restrict__ gw,
                                                 const float* __restrict__ gb,
                                                 unsigned short* __restrict__ h_t) {
  int g = blockIdx.x, b = blockIdx.y;
  int t = threadIdx.x;
  const float* xb = x + ((size_t)b * CC + g * 8) * NN;

  float vals[8][4];
  float s = 0.f, sq = 0.f;
#pragma unroll
  for (int cc = 0; cc < 8; cc++) {
    floatx4 v4 = *(const floatx4*)(xb + cc * NN + t * 4);
#pragma unroll
    for (int j = 0; j < 4; j++) {
      vals[cc][j] = v4[j];
      s += v4[j];
      sq += v4[j] * v4[j];
    }
  }
#pragma unroll
  for (int d = 1; d < 64; d <<= 1) {
    s  += __shfl_xor(s, d);
    sq += __shfl_xor(sq, d);
  }
  __shared__ float ssum[4], ssq[4];
  int w = t >> 6;
  if ((t & 63) == 0) { ssum[w] = s; ssq[w] = sq; }
  __syncthreads();
  s  = ssum[0] + ssum[1] + ssum[2] + ssum[3];
  sq = ssq[0] + ssq[1] + ssq[2] + ssq[3];
  float mean = s * (1.f / 8192.f);
  float var  = sq * (1.f / 8192.f) - mean * mean;
  float rstd = rsqrtf(var + 1e-5f);

  float gam[8], bet[8];
#pragma unroll
  for (int cc = 0; cc < 8; cc++) {
    float gm = gw[g * 8 + cc] * rstd;
    gam[cc] = gm;
    bet[cc] = gb[g * 8 + cc] - mean * gm;
  }
  unsigned short* hb = h_t + (size_t)b * NN * CC + g * 8;
#pragma unroll
  for (int j = 0; j < 4; j++) {
    ushortx8 pk;
#pragma unroll
    for (int cc = 0; cc < 8; cc++) pk[cc] = f2bf(vals[cc][j] * gam[cc] + bet[cc]);
    *(ushortx8*)(hb + (size_t)(t * 4 + j) * CC) = pk;
  }
}

// ---------------- QKV GEMM ----------------
__global__ __launch_bounds__(256) void qkv_gemm(const unsigned short* __restrict__ h_t,
                                                const unsigned short* __restrict__ wqkv,
                                                const float* __restrict__ bqkv,
                                                unsigned short* __restrict__ q_t,
                                                unsigned short* __restrict__ k_t,
                                                unsigned short* __restrict__ v) {
  int b = blockIdx.z;
  int n0 = blockIdx.y * 64, o0 = blockIdx.x * 64;
  int t = threadIdx.x, w = t >> 6, l = t & 63, lo = l & 15, h = l >> 4;
  int wr = w >> 1, wc = w & 1;
  const unsigned short* A = h_t + (size_t)b * NN * CC;
  int arow0 = n0 + wr * 32, bcol0 = o0 + wc * 32;

  floatx4 zero4 = {0.f, 0.f, 0.f, 0.f};
  floatx4 acc[2][2];
  acc[0][0] = zero4; acc[0][1] = zero4; acc[1][0] = zero4; acc[1][1] = zero4;

#pragma unroll
  for (int kc = 0; kc < 8; kc++) {
    int c0 = kc * 32 + h * 8;
    shortx8 a0 = *(const shortx8*)(A + (size_t)(arow0 + lo) * CC + c0);
    shortx8 a1 = *(const shortx8*)(A + (size_t)(arow0 + 16 + lo) * CC + c0);
    shortx8 b0 = *(const shortx8*)(wqkv + (size_t)(bcol0 + lo) * CC + c0);
    shortx8 b1 = *(const shortx8*)(wqkv + (size_t)(bcol0 + 16 + lo) * CC + c0);
    acc[0][0] = mfma16(a0, b0, acc[0][0]);
    acc[0][1] = mfma16(a0, b1, acc[0][1]);
    acc[1][0] = mfma16(a1, b0, acc[1][0]);
    acc[1][1] = mfma16(a1, b1, acc[1][1]);
  }
#pragma unroll
  for (int i = 0; i < 2; i++) {
#pragma unroll
    for (int j = 0; j < 2; j++) {
      int o = bcol0 + j * 16 + lo;
      float bias = bqkv[o];
      if (o < 512) {
#pragma unroll
        for (int r = 0; r < 4; r++) {
          int n = arow0 + i * 16 + h * 4 + r;
          float val = acc[i][j][r] + bias;
          if (o < 256)
            q_t[((size_t)b * NN + n) * CC + o] = f2bf(val);
          else
            k_t[((size_t)b * NN + n) * CC + (o - 256)] = f2bf(val);
        }
      } else {
        int n0r = arow0 + i * 16 + h * 4;
        ushortx4 pk;
#pragma unroll
        for (int r = 0; r < 4; r++) pk[r] = f2bf(acc[i][j][r] + bias);
        *(ushortx4*)(v + ((size_t)b * CC + (o - 512)) * NN + n0r) = pk;
      }
    }
  }
}

// ---------------- Flash attention (v2: swapped QK^T, register softmax, no LDS) ----------------
// block = 4 waves x 16 queries = 64 queries; grid 1024 blocks, XCD-swizzled so each
// XCD owns 8 batches (K/V ~1MB/batch stays L2-resident).
// Swapped QK^T: s[kt][r] = S[k = k0+kt*16+h*4+r][q = qbase+lo]  (lane-local softmax over k).
__global__ __launch_bounds__(256) void flash_kernel(const unsigned short* __restrict__ q_t,
                                                    const unsigned short* __restrict__ k_t,
                                                    const unsigned short* __restrict__ v,
                                                    unsigned short* __restrict__ attn_t) {
  int bid = blockIdx.x + (blockIdx.y << 4);          // 0..1023
  int wgid = ((bid & 7) << 7) + (bid >> 3);          // bijective XCD swizzle (1024 % 8 == 0)
  int b = wgid >> 4, qblk = wgid & 15;
  int t = threadIdx.x, w = t >> 6, l = t & 63, lo = l & 15, h = l >> 4;
  const unsigned short* qtb = q_t + (size_t)b * NN * CC;
  const unsigned short* ktb = k_t + (size_t)b * NN * CC;
  const unsigned short* vb  = v   + (size_t)b * CC * NN;
  int qbase = qblk * 64 + w * 16;

  shortx8 qf[8];
#pragma unroll
  for (int ch = 0; ch < 8; ch++)
    qf[ch] = *(const shortx8*)(qtb + (size_t)(qbase + lo) * CC + ch * 32 + h * 8);

  floatx4 zero4 = {0.f, 0.f, 0.f, 0.f};
  floatx4 o[16];
#pragma unroll
  for (int i = 0; i < 16; i++) o[i] = zero4;
  float m = -1e30f, lsum = 0.f;

  for (int kb = 0; kb < 16; kb++) {
    int k0 = kb * 64;
    floatx4 s[4];
#pragma unroll
    for (int i = 0; i < 4; i++) s[i] = zero4;
#pragma unroll
    for (int kt = 0; kt < 4; kt++) {
      const unsigned short* kp = ktb + (size_t)(k0 + kt * 16 + lo) * CC + h * 8;
#pragma unroll
      for (int ch = 0; ch < 8; ch++) {
        shortx8 kf = *(const shortx8*)(kp + ch * 32);
        s[kt] = mfma16(kf, qf[ch], s[kt]);   // swapped: A=K rows, B=Q rows
      }
    }
    // lane-local online softmax for q = qbase+lo (state replicated across h-groups)
    float pmax = fmaxf(fmaxf(fmaxf(s[0][0], s[0][1]), fmaxf(s[0][2], s[0][3])),
                       fmaxf(fmaxf(s[1][0], s[1][1]), fmaxf(s[1][2], s[1][3])));
    pmax = fmaxf(pmax, fmaxf(fmaxf(fmaxf(s[2][0], s[2][1]), fmaxf(s[2][2], s[2][3])),
                             fmaxf(fmaxf(s[3][0], s[3][1]), fmaxf(s[3][2], s[3][3]))));
    pmax = fmaxf(pmax, __shfl_xor(pmax, 16));
    pmax = fmaxf(pmax, __shfl_xor(pmax, 32));
    int nochange = __all(pmax <= m);
    float alpha = 0.f;
    if (!nochange) {
      float mn = fmaxf(m, pmax);
      alpha = __expf(m - mn);
      m = mn;
    }
    float rs = 0.f;
    unsigned int pk[4][2];
#pragma unroll
    for (int kt = 0; kt < 4; kt++) {
      float p0 = __expf(s[kt][0] - m);
      float p1 = __expf(s[kt][1] - m);
      float p2 = __expf(s[kt][2] - m);
      float p3 = __expf(s[kt][3] - m);
      rs += (p0 + p1) + (p2 + p3);
      pk[kt][0] = (unsigned)f2bf(p0) | ((unsigned)f2bf(p1) << 16);
      pk[kt][1] = (unsigned)f2bf(p2) | ((unsigned)f2bf(p3) << 16);
    }
    rs += __shfl_xor(rs, 16);
    rs += __shfl_xor(rs, 32);
    if (!nochange) {
      lsum = lsum * alpha + rs;
#pragma unroll
      for (int r = 0; r < 4; r++) {
        float ar = __shfl(alpha, (h << 4) + (h << 2) + r);  // alpha for q = h*4+r
#pragma unroll
        for (int cb = 0; cb < 16; cb++) o[cb][r] *= ar;
      }
    } else {
      lsum += rs;
    }
    // PV: gather P into A-fragment layout via packed shuffles, then 32 MFMA.
#pragma unroll
    for (int kk = 0; kk < 2; kk++) {
      // slot = kt index holding this lane-group's needed k-range
      unsigned int pk0 = (h & 2) ? pk[(kk << 1) + 1][0] : pk[kk << 1][0];
      unsigned int pk1 = (h & 2) ? pk[(kk << 1) + 1][1] : pk[kk << 1][1];
      unsigned int pa32[4];
#pragma unroll
      for (int jj = 0; jj < 4; jj++) {
        int hs = ((h << 1) + (jj >> 1)) & 3;
        pa32[jj] = __shfl((jj & 1) ? pk1 : pk0, lo + (hs << 4));
      }
      union { unsigned int u[4]; shortx8 v; } pa;
      pa.u[0] = pa32[0]; pa.u[1] = pa32[1]; pa.u[2] = pa32[2]; pa.u[3] = pa32[3];
      const unsigned short* vp = vb + k0 + (kk << 5) + (h << 3);
#pragma unroll
      for (int cb = 0; cb < 16; cb++) {
        shortx8 vf = *(const shortx8*)(vp + (size_t)((cb << 4) + lo) * NN);
        o[cb] = mfma16(pa.v, vf, o[cb]);
      }
    }
  }

  float rl[4];
#pragma unroll
  for (int r = 0; r < 4; r++) {
    float ls = __shfl(lsum, (h << 4) + (h << 2) + r);   // lsum for q = h*4+r
    rl[r] = 1.f / ls;
  }
  unsigned short* ab = attn_t + (size_t)b * NN * CC;
#pragma unroll
  for (int cb = 0; cb < 16; cb++) {
#pragma unroll
    for (int r = 0; r < 4; r++) {
      ab[(size_t)(qbase + (h << 2) + r) * CC + (cb << 4) + lo] = f2bf(o[cb][r] * rl[r]);
    }
  }
}

// ---------------- Out projection + bias + residual ----------------
__global__ __launch_bounds__(256) void outproj_gemm(const unsigned short* __restrict__ attn_t,
                                                    const unsigned short* __restrict__ wo_bf,
                                                    const float* __restrict__ bo,
                                                    const float* __restrict__ x,
                                                    float* __restrict__ out) {
  int b = blockIdx.z;
  int n0 = blockIdx.y * 64, o0 = blockIdx.x * 64;
  int t = threadIdx.x, w = t >> 6, l = t & 63, lo = l & 15, h = l >> 4;
  int wr = w >> 1, wc = w & 1;
  const unsigned short* A = attn_t + (size_t)b * NN * CC;
  int arow0 = n0 + wr * 32, bcol0 = o0 + wc * 32;

  floatx4 zero4 = {0.f, 0.f, 0.f, 0.f};
  floatx4 acc[2][2];
  acc[0][0] = zero4; acc[0][1] = zero4; acc[1][0] = zero4; acc[1][1] = zero4;

#pragma unroll
  for (int kc = 0; kc < 8; kc++) {
    int c0 = kc * 32 + h * 8;
    shortx8 a0 = *(const shortx8*)(A + (size_t)(arow0 + lo) * CC + c0);
    shortx8 a1 = *(const shortx8*)(A + (size_t)(arow0 + 16 + lo) * CC + c0);
    shortx8 b0 = *(const shortx8*)(wo_bf + (size_t)(bcol0 + lo) * CC + c0);
    shortx8 b1 = *(const shortx8*)(wo_bf + (size_t)(bcol0 + 16 + lo) * CC + c0);
    acc[0][0] = mfma16(a0, b0, acc[0][0]);
    acc[0][1] = mfma16(a0, b1, acc[0][1]);
    acc[1][0] = mfma16(a1, b0, acc[1][0]);
    acc[1][1] = mfma16(a1, b1, acc[1][1]);
  }
#pragma unroll
  for (int i = 0; i < 2; i++) {
#pragma unroll
    for (int j = 0; j < 2; j++) {
      int o = bcol0 + j * 16 + lo;
      int n = arow0 + i * 16 + h * 4;
      float bias = bo[o];
      size_t idx = ((size_t)b * CC + o) * NN + n;
      floatx4 xr = *(const floatx4*)(x + idx);
      floatx4 res;
#pragma unroll
      for (int r = 0; r < 4; r++) res[r] = acc[i][j][r] + bias + xr[r];
      *(floatx4*)(out + idx) = res;
    }
  }
}

extern "C" void kernel_launch(void* const* d_in, const int* in_sizes, int n_in,
                              void* d_out, int out_size, void* d_ws, size_t ws_size,
                              hipStream_t stream) {
  const float* x  = (const float*)d_in[0];
  const float* gw = (const float*)d_in[1];
  const float* gb = (const float*)d_in[2];
  const float* wq = (const float*)d_in[3];
  const float* bq = (const float*)d_in[4];
  const float* wk = (const float*)d_in[5];
  const float* bk = (const float*)d_in[6];
  const float* wv = (const float*)d_in[7];
  const float* bv = (const float*)d_in[8];
  const float* wo = (const float*)d_in[9];
  const float* bo = (const float*)d_in[10];
  float* out = (float*)d_out;

  char* ws = (char*)d_ws;
  unsigned short* q_t   = (unsigned short*)(ws);                 // 33554432 B
  unsigned short* k_t   = (unsigned short*)(ws + 33554432);      // 33554432 B
  unsigned short* v     = (unsigned short*)(ws + 67108864);      // 33554432 B
  unsigned short* h_t   = (unsigned short*)(ws + 100663296);     // 33554432 B (reused as attn_t)
  unsigned short* wqkv  = (unsigned short*)(ws + 134217728);     // 393216 B
  unsigned short* wo_bf = (unsigned short*)(ws + 134610944);     // 131072 B
  float*          bqkv  = (float*)(ws + 134742016);              // 3072 B
  unsigned short* attn_t = h_t;

  convert_w<<<dim3(1027), dim3(256), 0, stream>>>(wq, bq, wk, bk, wv, bv, wo, wqkv, wo_bf, bqkv);
  gn_kernel<<<dim3(32, 64), dim3(256), 0, stream>>>(x, gw, gb, h_t);
  qkv_gemm<<<dim3(12, 16, 64), dim3(256), 0, stream>>>(h_t, wqkv, bqkv, q_t, k_t, v);
  flash_kernel<<<dim3(16, 64), dim3(256), 0, stream>>>(q_t, k_t, v, attn_t);
  outproj_gemm<<<dim3(4, 16, 64), dim3(256), 0, stream>>>(attn_t, wo_bf, bo, x, out);
}

// Round 3
// 472.127 us; speedup vs baseline: 1.8679x; 1.6252x over previous
//
#include <hip/hip_runtime.h>

// Problem: B=64, C=256, H=W=32 -> N=1024 positions, 32 groups.
// Pipeline: GN -> qkv proj -> attention (d=256, seq=1024, per batch) -> out proj -> residual.
// All matmuls in bf16 MFMA (16x16x32). q scaled by C^-0.5=1/16 folded into wq/bq.

#define BB 64
#define CC 256
#define NN 1024

typedef float  floatx4  __attribute__((ext_vector_type(4)));
typedef short  shortx8  __attribute__((ext_vector_type(8)));
typedef unsigned short ushortx4 __attribute__((ext_vector_type(4)));
typedef unsigned short ushortx8 __attribute__((ext_vector_type(8)));

__device__ __forceinline__ unsigned short f2bf(float f) {
  union { float f; unsigned int u; } cv; cv.f = f;
  unsigned int u = cv.u;
  u += 0x7fffu + ((u >> 16) & 1u);
  return (unsigned short)(u >> 16);
}

__device__ __forceinline__ floatx4 mfma16(shortx8 a, shortx8 b, floatx4 c) {
  return __builtin_amdgcn_mfma_f32_16x16x32_bf16(a, b, c, 0, 0, 0);
}

// async global->LDS, 16B per lane. LDS dest = wave-uniform base + lane*16 (linear);
// swizzling is done on the GLOBAL source address (rule #21: both-sides-or-neither).
__device__ __forceinline__ void gload16(const unsigned short* g, unsigned short* s) {
  __builtin_amdgcn_global_load_lds(
      reinterpret_cast<const __attribute__((address_space(1))) void*>(
          (unsigned long long)g),
      reinterpret_cast<__attribute__((address_space(3))) void*>(
          (unsigned int)(unsigned long long)s),
      16, 0, 0);
}

// ---------------- weight conversion ----------------
__global__ void convert_w(const float* __restrict__ wq, const float* __restrict__ bq,
                          const float* __restrict__ wk, const float* __restrict__ bk,
                          const float* __restrict__ wv, const float* __restrict__ bv,
                          const float* __restrict__ wo,
                          unsigned short* __restrict__ wqkv,
                          unsigned short* __restrict__ wo_bf,
                          float* __restrict__ bqkv) {
  int i = blockIdx.x * 256 + threadIdx.x;
  if (i < 196608) {
    int o = i >> 8, c = i & 255;
    float val;
    if (o < 256)      val = wq[o * 256 + c] * 0.0625f;
    else if (o < 512) val = wk[(o - 256) * 256 + c];
    else              val = wv[(o - 512) * 256 + c];
    wqkv[i] = f2bf(val);
  } else if (i < 262144) {
    int j = i - 196608;
    wo_bf[j] = f2bf(wo[j]);
  } else if (i < 262912) {
    int o = i - 262144;
    float val;
    if (o < 256)      val = bq[o] * 0.0625f;
    else if (o < 512) val = bk[o - 256];
    else              val = bv[o - 512];
    bqkv[o] = val;
  }
}

// ---------------- GroupNorm -> h_t (B, N, C) bf16 ----------------
__global__ __launch_bounds__(256) void gn_kernel(const float* __restrict__ x,
                                                 const float* __restrict__ gw,
                                                 const float* __restrict__ gb,
                                                 unsigned short* __restrict__ h_t) {
  int g = blockIdx.x, b = blockIdx.y;
  int t = threadIdx.x;
  const float* xb = x + ((size_t)b * CC + g * 8) * NN;

  float vals[8][4];
  float s = 0.f, sq = 0.f;
#pragma unroll
  for (int cc = 0; cc < 8; cc++) {
    floatx4 v4 = *(const floatx4*)(xb + cc * NN + t * 4);
#pragma unroll
    for (int j = 0; j < 4; j++) {
      vals[cc][j] = v4[j];
      s += v4[j];
      sq += v4[j] * v4[j];
    }
  }
#pragma unroll
  for (int d = 1; d < 64; d <<= 1) {
    s  += __shfl_xor(s, d);
    sq += __shfl_xor(sq, d);
  }
  __shared__ float ssum[4], ssq[4];
  int w = t >> 6;
  if ((t & 63) == 0) { ssum[w] = s; ssq[w] = sq; }
  __syncthreads();
  s  = ssum[0] + ssum[1] + ssum[2] + ssum[3];
  sq = ssq[0] + ssq[1] + ssq[2] + ssq[3];
  float mean = s * (1.f / 8192.f);
  float var  = sq * (1.f / 8192.f) - mean * mean;
  float rstd = rsqrtf(var + 1e-5f);

  float gam[8], bet[8];
#pragma unroll
  for (int cc = 0; cc < 8; cc++) {
    float gm = gw[g * 8 + cc] * rstd;
    gam[cc] = gm;
    bet[cc] = gb[g * 8 + cc] - mean * gm;
  }
  unsigned short* hb = h_t + (size_t)b * NN * CC + g * 8;
#pragma unroll
  for (int j = 0; j < 4; j++) {
    ushortx8 pk;
#pragma unroll
    for (int cc = 0; cc < 8; cc++) pk[cc] = f2bf(vals[cc][j] * gam[cc] + bet[cc]);
    *(ushortx8*)(hb + (size_t)(t * 4 + j) * CC) = pk;
  }
}

// ---------------- QKV GEMM ----------------
__global__ __launch_bounds__(256) void qkv_gemm(const unsigned short* __restrict__ h_t,
                                                const unsigned short* __restrict__ wqkv,
                                                const float* __restrict__ bqkv,
                                                unsigned short* __restrict__ q_t,
                                                unsigned short* __restrict__ k_t,
                                                unsigned short* __restrict__ v) {
  int b = blockIdx.z;
  int n0 = blockIdx.y * 64, o0 = blockIdx.x * 64;
  int t = threadIdx.x, w = t >> 6, l = t & 63, lo = l & 15, h = l >> 4;
  int wr = w >> 1, wc = w & 1;
  const unsigned short* A = h_t + (size_t)b * NN * CC;
  int arow0 = n0 + wr * 32, bcol0 = o0 + wc * 32;

  floatx4 zero4 = {0.f, 0.f, 0.f, 0.f};
  floatx4 acc[2][2];
  acc[0][0] = zero4; acc[0][1] = zero4; acc[1][0] = zero4; acc[1][1] = zero4;

#pragma unroll
  for (int kc = 0; kc < 8; kc++) {
    int c0 = kc * 32 + h * 8;
    shortx8 a0 = *(const shortx8*)(A + (size_t)(arow0 + lo) * CC + c0);
    shortx8 a1 = *(const shortx8*)(A + (size_t)(arow0 + 16 + lo) * CC + c0);
    shortx8 b0 = *(const shortx8*)(wqkv + (size_t)(bcol0 + lo) * CC + c0);
    shortx8 b1 = *(const shortx8*)(wqkv + (size_t)(bcol0 + 16 + lo) * CC + c0);
    acc[0][0] = mfma16(a0, b0, acc[0][0]);
    acc[0][1] = mfma16(a0, b1, acc[0][1]);
    acc[1][0] = mfma16(a1, b0, acc[1][0]);
    acc[1][1] = mfma16(a1, b1, acc[1][1]);
  }
#pragma unroll
  for (int i = 0; i < 2; i++) {
#pragma unroll
    for (int j = 0; j < 2; j++) {
      int o = bcol0 + j * 16 + lo;
      float bias = bqkv[o];
      if (o < 512) {
#pragma unroll
        for (int r = 0; r < 4; r++) {
          int n = arow0 + i * 16 + h * 4 + r;
          float val = acc[i][j][r] + bias;
          if (o < 256)
            q_t[((size_t)b * NN + n) * CC + o] = f2bf(val);
          else
            k_t[((size_t)b * NN + n) * CC + (o - 256)] = f2bf(val);
        }
      } else {
        int n0r = arow0 + i * 16 + h * 4;
        ushortx4 pk;
#pragma unroll
        for (int r = 0; r < 4; r++) pk[r] = f2bf(acc[i][j][r] + bias);
        *(ushortx4*)(v + ((size_t)b * CC + (o - 512)) * NN + n0r) = pk;
      }
    }
  }
}

// ---------------- Flash attention v3: LDS-staged K/V tiles ----------------
// block = 4 waves x 16 queries = 64 queries; per 64-key tile, K(64x256,32KB) and
// V(256x64,32KB) are staged via global_load_lds (coalesced, source-pre-swizzled),
// fragments read as swizzled ds_read_b128 (2-way conflicts only = free).
__global__ __launch_bounds__(256) void flash_kernel(const unsigned short* __restrict__ q_t,
                                                    const unsigned short* __restrict__ k_t,
                                                    const unsigned short* __restrict__ v,
                                                    unsigned short* __restrict__ attn_t) {
  __shared__ __align__(16) unsigned short kbuf[64 * 256];   // row=512B, 32 chunks of 16B
  __shared__ __align__(16) unsigned short vbuf[256 * 64];   // row=128B, 8 chunks of 16B
  int bid = blockIdx.x + (blockIdx.y << 4);          // 0..1023
  int wgid = ((bid & 7) << 7) + (bid >> 3);          // bijective XCD swizzle
  int b = wgid >> 4, qblk = wgid & 15;
  int t = threadIdx.x, w = t >> 6, l = t & 63, lo = l & 15, h = l >> 4;
  const unsigned short* qtb = q_t + (size_t)b * NN * CC;
  const unsigned short* ktb = k_t + (size_t)b * NN * CC;
  const unsigned short* vb  = v   + (size_t)b * CC * NN;
  int qbase = qblk * 64 + w * 16;

  shortx8 qf[8];
#pragma unroll
  for (int ch = 0; ch < 8; ch++)
    qf[ch] = *(const shortx8*)(qtb + (size_t)(qbase + lo) * CC + ch * 32 + h * 8);

  floatx4 zero4 = {0.f, 0.f, 0.f, 0.f};
  floatx4 o[16];
#pragma unroll
  for (int i = 0; i < 16; i++) o[i] = zero4;
  float m = -1e30f, lsum = 0.f;

  // staging geometry (per wave)
  int krow_l = (w << 4) + (l >> 5);   // + i*2  : K tile rows w*16..w*16+15
  int kchunk = l & 31;
  int vrow_l = (w << 6) + (l >> 3);   // + i*8  : V tile rows w*64..w*64+63
  int vchunk = l & 7;

  for (int kb = 0; kb < 16; kb++) {
    int k0 = kb * 64;
    // ---- stage K tile (8 instr/wave, 1KB each, coalesced) ----
#pragma unroll
    for (int i = 0; i < 8; i++) {
      int row = krow_l + i * 2;
      gload16(ktb + (size_t)(k0 + row) * CC + ((kchunk ^ (row & 7)) << 3),
              &kbuf[((w << 4) + i * 2) << 8]);
    }
    // ---- stage V tile ----
#pragma unroll
    for (int i = 0; i < 8; i++) {
      int row = vrow_l + i * 8;
      gload16(vb + (size_t)row * NN + k0 + ((vchunk ^ (row & 7)) << 3),
              &vbuf[((w << 6) + i * 8) << 6]);
    }
    __syncthreads();   // vmcnt drain + visibility

    // ---- QK^T from LDS (swapped: A=K rows, B=Q rows) ----
    floatx4 s[4];
#pragma unroll
    for (int i = 0; i < 4; i++) s[i] = zero4;
#pragma unroll
    for (int kt = 0; kt < 4; kt++) {
      const unsigned short* kp = &kbuf[(kt * 16 + lo) << 8];
#pragma unroll
      for (int ch = 0; ch < 8; ch++) {
        shortx8 kf = *(const shortx8*)(kp + (((ch * 4 + h) ^ (lo & 7)) << 3));
        s[kt] = mfma16(kf, qf[ch], s[kt]);
      }
    }
    // ---- lane-local online softmax for q = qbase+lo ----
    float pmax = fmaxf(fmaxf(fmaxf(s[0][0], s[0][1]), fmaxf(s[0][2], s[0][3])),
                       fmaxf(fmaxf(s[1][0], s[1][1]), fmaxf(s[1][2], s[1][3])));
    pmax = fmaxf(pmax, fmaxf(fmaxf(fmaxf(s[2][0], s[2][1]), fmaxf(s[2][2], s[2][3])),
                             fmaxf(fmaxf(s[3][0], s[3][1]), fmaxf(s[3][2], s[3][3]))));
    pmax = fmaxf(pmax, __shfl_xor(pmax, 16));
    pmax = fmaxf(pmax, __shfl_xor(pmax, 32));
    int nochange = __all(pmax <= m);
    float alpha = 0.f;
    if (!nochange) {
      float mn = fmaxf(m, pmax);
      alpha = __expf(m - mn);
      m = mn;
    }
    float rs = 0.f;
    unsigned int pk[4][2];
#pragma unroll
    for (int kt = 0; kt < 4; kt++) {
      float p0 = __expf(s[kt][0] - m);
      float p1 = __expf(s[kt][1] - m);
      float p2 = __expf(s[kt][2] - m);
      float p3 = __expf(s[kt][3] - m);
      rs += (p0 + p1) + (p2 + p3);
      pk[kt][0] = (unsigned)f2bf(p0) | ((unsigned)f2bf(p1) << 16);
      pk[kt][1] = (unsigned)f2bf(p2) | ((unsigned)f2bf(p3) << 16);
    }
    rs += __shfl_xor(rs, 16);
    rs += __shfl_xor(rs, 32);
    if (!nochange) {
      lsum = lsum * alpha + rs;
#pragma unroll
      for (int r = 0; r < 4; r++) {
        float ar = __shfl(alpha, (h << 4) + (h << 2) + r);
#pragma unroll
        for (int cb = 0; cb < 16; cb++) o[cb][r] *= ar;
      }
    } else {
      lsum += rs;
    }
    // ---- PV from LDS: gather P via packed shuffles (proven block, unchanged) ----
#pragma unroll
    for (int kk = 0; kk < 2; kk++) {
      unsigned int pk0 = (h & 2) ? pk[(kk << 1) + 1][0] : pk[kk << 1][0];
      unsigned int pk1 = (h & 2) ? pk[(kk << 1) + 1][1] : pk[kk << 1][1];
      unsigned int pa32[4];
#pragma unroll
      for (int jj = 0; jj < 4; jj++) {
        int hs = ((h << 1) + (jj >> 1)) & 3;
        pa32[jj] = __shfl((jj & 1) ? pk1 : pk0, lo + (hs << 4));
      }
      union { unsigned int u[4]; shortx8 v; } pa;
      pa.u[0] = pa32[0]; pa.u[1] = pa32[1]; pa.u[2] = pa32[2]; pa.u[3] = pa32[3];
#pragma unroll
      for (int cb = 0; cb < 16; cb++) {
        shortx8 vf = *(const shortx8*)(&vbuf[(((cb << 4) + lo) << 6) +
                                             ((((kk << 2) + h) ^ (lo & 7)) << 3)]);
        o[cb] = mfma16(pa.v, vf, o[cb]);
      }
    }
    __syncthreads();   // all reads done before next stage overwrites
  }

  float rl[4];
#pragma unroll
  for (int r = 0; r < 4; r++) {
    float ls = __shfl(lsum, (h << 4) + (h << 2) + r);
    rl[r] = 1.f / ls;
  }
  // ---- epilogue: repack O through per-wave LDS region, coalesced global stores ----
  unsigned short* ow = &kbuf[w << 12];   // 8KB per wave: [16 q][256 c], swizzled
#pragma unroll
  for (int cb = 0; cb < 16; cb++) {
#pragma unroll
    for (int r = 0; r < 4; r++) {
      int q = (h << 2) + r;
      int c = (cb << 4) + lo;
      int sw = (q ^ (q >> 3)) & 7;
      ow[(q << 8) + (((c >> 3) ^ sw) << 3) + (lo & 7)] = f2bf(o[cb][r] * rl[r]);
    }
  }
  __syncthreads();
  unsigned short* ab = attn_t + (size_t)b * NN * CC;
#pragma unroll
  for (int it = 0; it < 8; it++) {
    int q = (it << 1) + (l >> 5);
    int gc = l & 31;
    int sw = (q ^ (q >> 3)) & 7;
    ushortx8 vv = *(const ushortx8*)(&ow[(q << 8) + ((gc ^ sw) << 3)]);
    *(ushortx8*)(ab + (size_t)(qbase + q) * CC + (gc << 3)) = vv;
  }
}

// ---------------- Out projection + bias + residual ----------------
__global__ __launch_bounds__(256) void outproj_gemm(const unsigned short* __restrict__ attn_t,
                                                    const unsigned short* __restrict__ wo_bf,
                                                    const float* __restrict__ bo,
                                                    const float* __restrict__ x,
                                                    float* __restrict__ out) {
  int b = blockIdx.z;
  int n0 = blockIdx.y * 64, o0 = blockIdx.x * 64;
  int t = threadIdx.x, w = t >> 6, l = t & 63, lo = l & 15, h = l >> 4;
  int wr = w >> 1, wc = w & 1;
  const unsigned short* A = attn_t + (size_t)b * NN * CC;
  int arow0 = n0 + wr * 32, bcol0 = o0 + wc * 32;

  floatx4 zero4 = {0.f, 0.f, 0.f, 0.f};
  floatx4 acc[2][2];
  acc[0][0] = zero4; acc[0][1] = zero4; acc[1][0] = zero4; acc[1][1] = zero4;

#pragma unroll
  for (int kc = 0; kc < 8; kc++) {
    int c0 = kc * 32 + h * 8;
    shortx8 a0 = *(const shortx8*)(A + (size_t)(arow0 + lo) * CC + c0);
    shortx8 a1 = *(const shortx8*)(A + (size_t)(arow0 + 16 + lo) * CC + c0);
    shortx8 b0 = *(const shortx8*)(wo_bf + (size_t)(bcol0 + lo) * CC + c0);
    shortx8 b1 = *(const shortx8*)(wo_bf + (size_t)(bcol0 + 16 + lo) * CC + c0);
    acc[0][0] = mfma16(a0, b0, acc[0][0]);
    acc[0][1] = mfma16(a0, b1, acc[0][1]);
    acc[1][0] = mfma16(a1, b0, acc[1][0]);
    acc[1][1] = mfma16(a1, b1, acc[1][1]);
  }
#pragma unroll
  for (int i = 0; i < 2; i++) {
#pragma unroll
    for (int j = 0; j < 2; j++) {
      int o = bcol0 + j * 16 + lo;
      int n = arow0 + i * 16 + h * 4;
      float bias = bo[o];
      size_t idx = ((size_t)b * CC + o) * NN + n;
      floatx4 xr = *(const floatx4*)(x + idx);
      floatx4 res;
#pragma unroll
      for (int r = 0; r < 4; r++) res[r] = acc[i][j][r] + bias + xr[r];
      *(floatx4*)(out + idx) = res;
    }
  }
}

extern "C" void kernel_launch(void* const* d_in, const int* in_sizes, int n_in,
                              void* d_out, int out_size, void* d_ws, size_t ws_size,
                              hipStream_t stream) {
  const float* x  = (const float*)d_in[0];
  const float* gw = (const float*)d_in[1];
  const float* gb = (const float*)d_in[2];
  const float* wq = (const float*)d_in[3];
  const float* bq = (const float*)d_in[4];
  const float* wk = (const float*)d_in[5];
  const float* bk = (const float*)d_in[6];
  const float* wv = (const float*)d_in[7];
  const float* bv = (const float*)d_in[8];
  const float* wo = (const float*)d_in[9];
  const float* bo = (const float*)d_in[10];
  float* out = (float*)d_out;

  char* ws = (char*)d_ws;
  unsigned short* q_t   = (unsigned short*)(ws);                 // 33554432 B
  unsigned short* k_t   = (unsigned short*)(ws + 33554432);      // 33554432 B
  unsigned short* v     = (unsigned short*)(ws + 67108864);      // 33554432 B
  unsigned short* h_t   = (unsigned short*)(ws + 100663296);     // 33554432 B (reused as attn_t)
  unsigned short* wqkv  = (unsigned short*)(ws + 134217728);     // 393216 B
  unsigned short* wo_bf = (unsigned short*)(ws + 134610944);     // 131072 B
  float*          bqkv  = (float*)(ws + 134742016);              // 3072 B
  unsigned short* attn_t = h_t;

  convert_w<<<dim3(1027), dim3(256), 0, stream>>>(wq, bq, wk, bk, wv, bv, wo, wqkv, wo_bf, bqkv);
  gn_kernel<<<dim3(32, 64), dim3(256), 0, stream>>>(x, gw, gb, h_t);
  qkv_gemm<<<dim3(12, 16, 64), dim3(256), 0, stream>>>(h_t, wqkv, bqkv, q_t, k_t, v);
  flash_kernel<<<dim3(16, 64), dim3(256), 0, stream>>>(q_t, k_t, v, attn_t);
  outproj_gemm<<<dim3(4, 16, 64), dim3(256), 0, stream>>>(attn_t, wo_bf, bo, x, out);
}